// Round 6
// baseline (458.060 us; speedup 1.0000x reference)
//
#include <hip/hip_runtime.h>
#include <hip/hip_bf16.h>

// Hopfield sparsemax attention, MI355X gfx950.
// B=1, L=S=2048, D_MODEL=1024, H=16, DK=64. Inputs fp32 (runtime-detected), output per flag.
//
// Round-6 structure: attention core fully fused, scores never hit HBM.
//   0.  detect dtype -> flag
//   p1. Qc/Kc = bf16(queries/keys)        [2048,1024]
//   p2. W*T = bf16(W^T)                   [1024,1024] x4 (LDS-tiled transpose)
//   1-3. Kb/Qb/Vb projections             (128-tile bf16 GEMM; Vb from Kb — ref quirk)
//   4.  attn_fused_k: per (head, 32-row strip):
//         sweep1: QK^T row maxes (MFMA + cross-lane max + LDS atomicMax)
//         sweep2: recompute, append candidates z >= M-1 (exact sparsemax support superset)
//         Michelot tau per row on candidates; PV = sparse gather of V rows; Ob bf16
//   5.  out = Ob @ WoT + bo -> d_out

typedef __attribute__((ext_vector_type(8))) short short8;
typedef __attribute__((ext_vector_type(4))) float floatx4;

#define SRC_BF16 0
#define SRC_F32  1
#define SRC_RT   2
#define CAP 192

__device__ __forceinline__ short f2bf(float f) {
    __hip_bfloat16 h = __float2bfloat16(f);
    return *reinterpret_cast<const short*>(&h);
}
__device__ __forceinline__ float bf2f(unsigned short u) {
    return __uint_as_float(((unsigned)u) << 16);
}
// monotone float->uint map (order-preserving for all finite floats)
__device__ __forceinline__ unsigned fmap(float f) {
    unsigned u = __float_as_uint(f);
    return (u & 0x80000000u) ? ~u : (u | 0x80000000u);
}
__device__ __forceinline__ float funmap(unsigned u) {
    return (u & 0x80000000u) ? __uint_as_float(u ^ 0x80000000u) : __uint_as_float(~u);
}

// Detect input dtype: decode first n shorts as bf16; fp32-read-as-bf16 almost surely
// yields |x|>1e10 / inf / NaN. One 64-thread block.
__global__ void detect_k(const short* __restrict__ q, int n, int* __restrict__ flag)
{
    const int tid = threadIdx.x;
    int bad = 0;
    for (int i = tid; i < n; i += 64) {
        float f = bf2f((unsigned short)q[i]);
        if (!(fabsf(f) < 1e10f)) bad = 1;
    }
    unsigned long long m = __ballot(bad != 0);
    if (tid == 0) *flag = (m != 0ULL) ? 1 : 0;
}

// Flat convert (fp32|bf16 per flag) -> bf16. z selects one of two sources.
__global__ __launch_bounds__(256)
void convert2_k(const void* __restrict__ s0, const void* __restrict__ s1,
                short* __restrict__ d0, short* __restrict__ d1,
                const int* __restrict__ dflag)
{
    const void* s = blockIdx.z ? s1 : s0;
    short* d = blockIdx.z ? d1 : d0;
    const size_t i = ((size_t)blockIdx.x * 256 + threadIdx.x) * 8;
    short8 o;
    if (*dflag) {
        const float4 f0 = ((const float4*)((const float*)s + i))[0];
        const float4 f1 = ((const float4*)((const float*)s + i))[1];
        o[0] = f2bf(f0.x); o[1] = f2bf(f0.y); o[2] = f2bf(f0.z); o[3] = f2bf(f0.w);
        o[4] = f2bf(f1.x); o[5] = f2bf(f1.y); o[6] = f2bf(f1.z); o[7] = f2bf(f1.w);
    } else {
        o = *(const short8*)((const short*)s + i);
    }
    *(short8*)(d + i) = o;
}

// Batched weight transpose: 4 matrices [R,C] -> bf16 [C,R], selected by blockIdx.z.
struct TP4 {
    const void* s[4];
    short* d[4];
};
__global__ __launch_bounds__(256)
void transpose4_k(TP4 p, int R, int C, const int* __restrict__ dflag)
{
    __shared__ short T[64][72];
    const int tid = threadIdx.x;
    const int bC = blockIdx.x, bR = blockIdx.y;
    const void* src = p.s[blockIdx.z];
    short* dst = p.d[blockIdx.z];
    const bool f32 = (*dflag != 0);

    const int colg = (tid & 7) * 8;
    #pragma unroll
    for (int h = 0; h < 2; ++h) {
        const int row = (tid >> 3) + 32 * h;
        const size_t idx = (size_t)(bR * 64 + row) * (size_t)C + (size_t)(bC * 64 + colg);
        short e[8];
        if (f32) {
            const float4 f0 = ((const float4*)((const float*)src + idx))[0];
            const float4 f1 = ((const float4*)((const float*)src + idx))[1];
            e[0] = f2bf(f0.x); e[1] = f2bf(f0.y); e[2] = f2bf(f0.z); e[3] = f2bf(f0.w);
            e[4] = f2bf(f1.x); e[5] = f2bf(f1.y); e[6] = f2bf(f1.z); e[7] = f2bf(f1.w);
        } else {
            short8 s = *(const short8*)((const short*)src + idx);
            #pragma unroll
            for (int j = 0; j < 8; ++j) e[j] = s[j];
        }
        #pragma unroll
        for (int j = 0; j < 8; ++j) T[colg + j][row] = e[j];
    }
    __syncthreads();
    #pragma unroll
    for (int h = 0; h < 2; ++h) {
        const int orow = (tid >> 3) + 32 * h;
        const int ocolg = (tid & 7) * 8;
        const size_t idx = (size_t)(bC * 64 + orow) * (size_t)R + (size_t)(bR * 64 + ocolg);
        *(short8*)(dst + idx) = *(const short8*)&T[orow][ocolg];
    }
}

// ---------------- 128x128-tile GEMM: bf16 A [M,K] x bf16 Bt [N,K] ----------------
template<int OSRC, bool HAS_BIAS>
__global__ __launch_bounds__(256)
void gemm128_bt_k(const short* __restrict__ Ap, long lda,
                  const short* __restrict__ Bp, long ldb,
                  const void* __restrict__ bias,
                  void* __restrict__ Cp, long ldc,
                  int K, float alpha, const int* __restrict__ dflag)
{
    __shared__ __align__(16) short As[128][40];
    __shared__ __align__(16) short Bs[128][40];

    int rtf = 0;
    if (OSRC == SRC_RT || HAS_BIAS) rtf = *dflag;

    const int tid  = threadIdx.x;
    const int bN   = blockIdx.x, bM = blockIdx.y;
    const int lane = tid & 63, wave = tid >> 6;
    const int wm   = (wave >> 1) * 64;
    const int wn   = (wave & 1) * 64;
    const int quad = lane >> 4, r16 = lane & 15;

    floatx4 acc[4][4];
    #pragma unroll
    for (int i = 0; i < 4; ++i)
        #pragma unroll
        for (int j = 0; j < 4; ++j)
            acc[i][j] = (floatx4){0.f, 0.f, 0.f, 0.f};

    const int ar = tid >> 2, ac = (tid & 3) * 8;

    for (int k0 = 0; k0 < K; k0 += 32) {
        #pragma unroll
        for (int c = 0; c < 2; ++c) {
            const int row = c * 64 + ar;
            *(short8*)&As[row][ac] =
                *(const short8*)(Ap + (size_t)(bM * 128 + row) * (size_t)lda + (size_t)(k0 + ac));
            *(short8*)&Bs[row][ac] =
                *(const short8*)(Bp + (size_t)(bN * 128 + row) * (size_t)ldb + (size_t)(k0 + ac));
        }
        __syncthreads();

        short8 af[4], bfr[4];
        #pragma unroll
        for (int i = 0; i < 4; ++i) af[i]  = *(const short8*)&As[wm + i * 16 + r16][quad * 8];
        #pragma unroll
        for (int j = 0; j < 4; ++j) bfr[j] = *(const short8*)&Bs[wn + j * 16 + r16][quad * 8];
        #pragma unroll
        for (int i = 0; i < 4; ++i)
            #pragma unroll
            for (int j = 0; j < 4; ++j)
                acc[i][j] = __builtin_amdgcn_mfma_f32_16x16x32_bf16(af[i], bfr[j], acc[i][j], 0, 0, 0);
        __syncthreads();
    }

    const bool of32 = (OSRC == SRC_F32) || (OSRC == SRC_RT && rtf);
    #pragma unroll
    for (int j = 0; j < 4; ++j) {
        const int gc = bN * 128 + wn + j * 16 + r16;
        float bb = 0.0f;
        if (HAS_BIAS)
            bb = rtf ? ((const float*)bias)[gc]
                     : __bfloat162float(((const __hip_bfloat16*)bias)[gc]);
        #pragma unroll
        for (int i = 0; i < 4; ++i) {
            #pragma unroll
            for (int rg = 0; rg < 4; ++rg) {
                const int gr = bM * 128 + wm + i * 16 + quad * 4 + rg;
                float v = acc[i][j][rg] * alpha + bb;
                if (of32)
                    ((float*)Cp)[(size_t)gr * (size_t)ldc + gc] = v;
                else
                    ((__hip_bfloat16*)Cp)[(size_t)gr * (size_t)ldc + gc] = __float2bfloat16(v);
            }
        }
    }
}

// ---------------- fused attention: QK^T -> sparsemax -> PV, scores never in HBM -----
// Block = 32 Q-rows x 1 head, 256 threads (4 waves). Wave w: row strip sp=(w>>1)*16,
// col-tile half hf=w&1. Sweep 1 computes exact row maxes; sweep 2 appends candidates
// z >= M-1 (superset of sparsemax support since p_max = M - tau <= 1). Michelot on
// candidates gives exact tau. PV is a sparse gather: out = sum_j p_j * V[idx_j].
__global__ __launch_bounds__(256)
void attn_fused_k(const short* __restrict__ Qb, const short* __restrict__ Kb,
                  const short* __restrict__ Vb, short* __restrict__ Ob)
{
    __shared__ __align__(16) short sQ[32][72];
    __shared__ __align__(16) short sK[128][72];
    __shared__ float cval[32][CAP];
    __shared__ unsigned short cidx[32][CAP];
    __shared__ unsigned rmax[32];
    __shared__ int cnt[32];
    __shared__ float stau[32];

    const int tid  = threadIdx.x;
    const int lane = tid & 63, wave = tid >> 6;
    const int quad = lane >> 4, r16 = lane & 15;
    const int row0 = blockIdx.x * 32;
    const int h    = blockIdx.y;
    const int sp   = (wave >> 1) * 16;
    const int hf   = wave & 1;

    if (tid < 32) { rmax[tid] = 0u; cnt[tid] = 0; }

    // stage Q strip [32 rows x 64 k]
    {
        const int r = tid >> 3, c = (tid & 7) * 8;
        *(short8*)&sQ[r][c] = *(const short8*)(Qb + (size_t)(row0 + r) * 1024 + h * 64 + c);
    }
    __syncthreads();

    const short8 a0 = *(const short8*)&sQ[sp + r16][quad * 8];
    const short8 a1 = *(const short8*)&sQ[sp + r16][32 + quad * 8];

    // ---- sweep 1: exact row maxes ----
    for (int s0 = 0; s0 < 2048; s0 += 128) {
        #pragma unroll
        for (int i = 0; i < 4; ++i) {
            const int kr = (tid >> 3) + 32 * i, c = (tid & 7) * 8;
            *(short8*)&sK[kr][c] = *(const short8*)(Kb + (size_t)(s0 + kr) * 1024 + h * 64 + c);
        }
        __syncthreads();
        #pragma unroll
        for (int t = 0; t < 4; ++t) {
            const int ct = (hf + 2 * t) * 16;
            const short8 b0 = *(const short8*)&sK[ct + r16][quad * 8];
            const short8 b1 = *(const short8*)&sK[ct + r16][32 + quad * 8];
            floatx4 acc = (floatx4){0.f, 0.f, 0.f, 0.f};
            acc = __builtin_amdgcn_mfma_f32_16x16x32_bf16(a0, b0, acc, 0, 0, 0);
            acc = __builtin_amdgcn_mfma_f32_16x16x32_bf16(a1, b1, acc, 0, 0, 0);
            #pragma unroll
            for (int rg = 0; rg < 4; ++rg) {
                float m = acc[rg] * 0.125f;
                #pragma unroll
                for (int off = 1; off < 16; off <<= 1)
                    m = fmaxf(m, __shfl_xor(m, off, 64));
                if (r16 == 0) atomicMax(&rmax[sp + quad * 4 + rg], fmap(m));
            }
        }
        __syncthreads();
    }

    // thresholds per lane's 4 rows
    float thr[4];
    #pragma unroll
    for (int rg = 0; rg < 4; ++rg) thr[rg] = funmap(rmax[sp + quad * 4 + rg]) - 1.0f;

    // ---- sweep 2: candidate append (z >= M-1) ----
    for (int s0 = 0; s0 < 2048; s0 += 128) {
        #pragma unroll
        for (int i = 0; i < 4; ++i) {
            const int kr = (tid >> 3) + 32 * i, c = (tid & 7) * 8;
            *(short8*)&sK[kr][c] = *(const short8*)(Kb + (size_t)(s0 + kr) * 1024 + h * 64 + c);
        }
        __syncthreads();
        #pragma unroll
        for (int t = 0; t < 4; ++t) {
            const int ct = (hf + 2 * t) * 16;
            const short8 b0 = *(const short8*)&sK[ct + r16][quad * 8];
            const short8 b1 = *(const short8*)&sK[ct + r16][32 + quad * 8];
            floatx4 acc = (floatx4){0.f, 0.f, 0.f, 0.f};
            acc = __builtin_amdgcn_mfma_f32_16x16x32_bf16(a0, b0, acc, 0, 0, 0);
            acc = __builtin_amdgcn_mfma_f32_16x16x32_bf16(a1, b1, acc, 0, 0, 0);
            #pragma unroll
            for (int rg = 0; rg < 4; ++rg) {
                const float val = acc[rg] * 0.125f;
                if (val >= thr[rg]) {
                    const int row = sp + quad * 4 + rg;
                    const int p = atomicAdd(&cnt[row], 1);
                    if (p < CAP) {
                        cval[row][p] = val;
                        cidx[row][p] = (unsigned short)(s0 + ct + r16);
                    }
                }
            }
        }
        __syncthreads();
    }

    // ---- Michelot tau per row (8 rows per wave, shuffle-only) ----
    for (int rr = 0; rr < 8; ++rr) {
        const int r = wave * 8 + rr;
        const int n = min(cnt[r], CAP);
        float c0[3];
        #pragma unroll
        for (int i = 0; i < 3; ++i) {
            const int ix = lane + i * 64;
            c0[i] = (ix < n) ? cval[r][ix] : -3.0e38f;
        }
        float tau = -3.0e38f, prevc = -1.0f;
        for (int it = 0; it < 48; ++it) {
            float s = 0.f, c = 0.f;
            #pragma unroll
            for (int i = 0; i < 3; ++i)
                if (c0[i] > tau) { s += c0[i]; c += 1.f; }
            #pragma unroll
            for (int off = 1; off < 64; off <<= 1) {
                s += __shfl_xor(s, off, 64);
                c += __shfl_xor(c, off, 64);
            }
            if (c == prevc) break;
            prevc = c;
            tau = (s - 1.0f) / c;
        }
        if (lane == 0) stau[r] = tau;
    }
    __syncthreads();

    // ---- PV sparse gather: lane = output col ----
    for (int rr = 0; rr < 8; ++rr) {
        const int r = wave * 8 + rr;
        const float tau = stau[r];
        const int n = min(cnt[r], CAP);
        float acc = 0.f;
        for (int j = 0; j < n; ++j) {
            const float p = cval[r][j] - tau;   // uniform across wave
            if (p > 0.f) {
                const int col = cidx[r][j];
                const unsigned short v =
                    ((const unsigned short*)Vb)[(size_t)col * 1024 + h * 64 + lane];
                acc += p * bf2f(v);
            }
        }
        Ob[((size_t)h * 2048 + row0 + r) * 64 + lane] = f2bf(acc);
    }
}

extern "C" void kernel_launch(void* const* d_in, const int* in_sizes, int n_in,
                              void* d_out, int out_size, void* d_ws, size_t ws_size,
                              hipStream_t stream)
{
    (void)in_sizes; (void)n_in; (void)out_size; (void)ws_size;

    const void* queries = d_in[0];
    const void* keys    = d_in[1];
    // d_in[2] ("values") unused by the reference.
    const void* Wq = d_in[3];
    const void* bq = d_in[4];
    const void* Wk = d_in[5];
    const void* bk = d_in[6];
    const void* Wv = d_in[7];
    const void* bv = d_in[8];
    const void* Wo = d_in[9];
    const void* bo = d_in[10];

    const int L = 2048, DM = 1024;
    const size_t LD = (size_t)L * DM;   // 2M elements

    int*   flag = (int*)d_ws;
    short* Qc  = (short*)((char*)d_ws + 256);  // bf16 queries      [2048,1024]
    short* Kc  = Qc + LD;                      // bf16 keys         [2048,1024]
    short* WqT = Kc + LD;                      // bf16 Wq^T         [1024,1024]
    short* WkT = WqT + (size_t)DM * DM;
    short* WvT = WkT + (size_t)DM * DM;
    short* WoT = WvT + (size_t)DM * DM;
    short* Qb  = WoT + (size_t)DM * DM;        // [2048,1024]
    short* Kb  = Qb + LD;
    short* Vb  = Kb + LD;
    short* Ob  = Vb + LD;                      // [H,2048,64] contiguous (== mixed view)

    dim3 blk(256);

    // 0) dtype detection
    detect_k<<<dim3(1), dim3(64), 0, stream>>>((const short*)queries, 4096, flag);

    // p1) convert queries/keys -> bf16
    convert2_k<<<dim3((unsigned)(LD / 2048), 1, 2), blk, 0, stream>>>(
        queries, keys, Qc, Kc, flag);

    // p2) transpose-convert the 4 weight matrices -> bf16 [N][K]
    {
        TP4 p;
        p.s[0] = Wq; p.s[1] = Wk; p.s[2] = Wv; p.s[3] = Wo;
        p.d[0] = WqT; p.d[1] = WkT; p.d[2] = WvT; p.d[3] = WoT;
        transpose4_k<<<dim3(DM / 64, DM / 64, 4), blk, 0, stream>>>(p, DM, DM, flag);
    }

    // 1) Kb = Kc @ WkT + bk
    gemm128_bt_k<SRC_BF16, true><<<dim3(DM / 128, L / 128), blk, 0, stream>>>(
        Kc, DM, WkT, DM, bk, Kb, DM, DM, 1.0f, flag);
    // 2) Qb = Qc @ WqT + bq
    gemm128_bt_k<SRC_BF16, true><<<dim3(DM / 128, L / 128), blk, 0, stream>>>(
        Qc, DM, WqT, DM, bq, Qb, DM, DM, 1.0f, flag);
    // 3) Vb = Kb @ WvT + bv   (reference quirk: V from key projection)
    gemm128_bt_k<SRC_BF16, true><<<dim3(DM / 128, L / 128), blk, 0, stream>>>(
        Kb, DM, WvT, DM, bv, Vb, DM, DM, 1.0f, flag);

    // 4) fused attention (scores never reach HBM)
    attn_fused_k<<<dim3(L / 32, 16), blk, 0, stream>>>(Qb, Kb, Vb, Ob);

    // 5) out = Ob(viewed [2048,1024]) @ WoT + bo -> d_out (dtype per flag)
    gemm128_bt_k<SRC_RT, true><<<dim3(DM / 128, L / 128), blk, 0, stream>>>(
        Ob, DM, WoT, DM, bo, d_out, DM, DM, 1.0f, flag);
}

// Round 8
// 357.544 us; speedup vs baseline: 1.2811x; 1.2811x over previous
//
#include <hip/hip_runtime.h>
#include <hip/hip_bf16.h>

// Hopfield sparsemax attention, MI355X gfx950.
// B=1, L=S=2048, D_MODEL=1024, H=16, DK=64. Inputs fp32 (runtime-detected), output per flag.
//
// Round-8: single-sweep fused attention with CAP=256 (round-7's CAP=128 overflowed on
// low-sigma rows: candidate count ~ P(z >= max-1) scales with row score std = |q|/8,
// chi2_64 tail puts rare rows at ~135-215 candidates; 256 covers with margin).
//   0.  detect dtype -> flag
//   p1. Qc/Kc = bf16(queries/keys)        [2048,1024]
//   p2. W*T = bf16(W^T)                   [1024,1024] x4 (LDS-tiled transpose)
//   1-3. Kb/Qb/Vb projections             (128-tile bf16 GEMM; Vb from Kb — ref quirk)
//   4.  attn_fused_k: block = 16 Q-rows x 1 head, 4 waves share rows, split cols.
//       Per 128-col K-tile: MFMA scores -> running row-max (atomicMax, barrier) ->
//       append candidates z >= rmax-1 (always superset of sparsemax support since
//       rmax <= M_final and support needs z > tau >= M_final-1). Michelot on candidates
//       -> exact tau; ballot-compact support; 4-deep unrolled sparse PV gather.
//   5.  out = Ob @ WoT + bo -> d_out

typedef __attribute__((ext_vector_type(8))) short short8;
typedef __attribute__((ext_vector_type(4))) float floatx4;

#define SRC_BF16 0
#define SRC_F32  1
#define SRC_RT   2
#define CAP 256

__device__ __forceinline__ short f2bf(float f) {
    __hip_bfloat16 h = __float2bfloat16(f);
    return *reinterpret_cast<const short*>(&h);
}
__device__ __forceinline__ float bf2f(unsigned short u) {
    return __uint_as_float(((unsigned)u) << 16);
}
// monotone float->uint map (order-preserving for all finite floats)
__device__ __forceinline__ unsigned fmap(float f) {
    unsigned u = __float_as_uint(f);
    return (u & 0x80000000u) ? ~u : (u | 0x80000000u);
}
__device__ __forceinline__ float funmap(unsigned u) {
    return (u & 0x80000000u) ? __uint_as_float(u ^ 0x80000000u) : __uint_as_float(~u);
}

// Detect input dtype: decode first n shorts as bf16; fp32-read-as-bf16 almost surely
// yields |x|>1e10 / inf / NaN. One 64-thread block.
__global__ void detect_k(const short* __restrict__ q, int n, int* __restrict__ flag)
{
    const int tid = threadIdx.x;
    int bad = 0;
    for (int i = tid; i < n; i += 64) {
        float f = bf2f((unsigned short)q[i]);
        if (!(fabsf(f) < 1e10f)) bad = 1;
    }
    unsigned long long m = __ballot(bad != 0);
    if (tid == 0) *flag = (m != 0ULL) ? 1 : 0;
}

// Flat convert (fp32|bf16 per flag) -> bf16. z selects one of two sources.
__global__ __launch_bounds__(256)
void convert2_k(const void* __restrict__ s0, const void* __restrict__ s1,
                short* __restrict__ d0, short* __restrict__ d1,
                const int* __restrict__ dflag)
{
    const void* s = blockIdx.z ? s1 : s0;
    short* d = blockIdx.z ? d1 : d0;
    const size_t i = ((size_t)blockIdx.x * 256 + threadIdx.x) * 8;
    short8 o;
    if (*dflag) {
        const float4 f0 = ((const float4*)((const float*)s + i))[0];
        const float4 f1 = ((const float4*)((const float*)s + i))[1];
        o[0] = f2bf(f0.x); o[1] = f2bf(f0.y); o[2] = f2bf(f0.z); o[3] = f2bf(f0.w);
        o[4] = f2bf(f1.x); o[5] = f2bf(f1.y); o[6] = f2bf(f1.z); o[7] = f2bf(f1.w);
    } else {
        o = *(const short8*)((const short*)s + i);
    }
    *(short8*)(d + i) = o;
}

// Batched weight transpose: 4 matrices [R,C] -> bf16 [C,R], selected by blockIdx.z.
struct TP4 {
    const void* s[4];
    short* d[4];
};
__global__ __launch_bounds__(256)
void transpose4_k(TP4 p, int R, int C, const int* __restrict__ dflag)
{
    __shared__ short T[64][72];
    const int tid = threadIdx.x;
    const int bC = blockIdx.x, bR = blockIdx.y;
    const void* src = p.s[blockIdx.z];
    short* dst = p.d[blockIdx.z];
    const bool f32 = (*dflag != 0);

    const int colg = (tid & 7) * 8;
    #pragma unroll
    for (int h = 0; h < 2; ++h) {
        const int row = (tid >> 3) + 32 * h;
        const size_t idx = (size_t)(bR * 64 + row) * (size_t)C + (size_t)(bC * 64 + colg);
        short e[8];
        if (f32) {
            const float4 f0 = ((const float4*)((const float*)src + idx))[0];
            const float4 f1 = ((const float4*)((const float*)src + idx))[1];
            e[0] = f2bf(f0.x); e[1] = f2bf(f0.y); e[2] = f2bf(f0.z); e[3] = f2bf(f0.w);
            e[4] = f2bf(f1.x); e[5] = f2bf(f1.y); e[6] = f2bf(f1.z); e[7] = f2bf(f1.w);
        } else {
            short8 s = *(const short8*)((const short*)src + idx);
            #pragma unroll
            for (int j = 0; j < 8; ++j) e[j] = s[j];
        }
        #pragma unroll
        for (int j = 0; j < 8; ++j) T[colg + j][row] = e[j];
    }
    __syncthreads();
    #pragma unroll
    for (int h = 0; h < 2; ++h) {
        const int orow = (tid >> 3) + 32 * h;
        const int ocolg = (tid & 7) * 8;
        const size_t idx = (size_t)(bC * 64 + orow) * (size_t)R + (size_t)(bR * 64 + ocolg);
        *(short8*)(dst + idx) = *(const short8*)&T[orow][ocolg];
    }
}

// ---------------- 128x128-tile GEMM: bf16 A [M,K] x bf16 Bt [N,K] ----------------
template<int OSRC, bool HAS_BIAS>
__global__ __launch_bounds__(256)
void gemm128_bt_k(const short* __restrict__ Ap, long lda,
                  const short* __restrict__ Bp, long ldb,
                  const void* __restrict__ bias,
                  void* __restrict__ Cp, long ldc,
                  int K, float alpha, const int* __restrict__ dflag)
{
    __shared__ __align__(16) short As[128][40];
    __shared__ __align__(16) short Bs[128][40];

    int rtf = 0;
    if (OSRC == SRC_RT || HAS_BIAS) rtf = *dflag;

    const int tid  = threadIdx.x;
    const int bN   = blockIdx.x, bM = blockIdx.y;
    const int lane = tid & 63, wave = tid >> 6;
    const int wm   = (wave >> 1) * 64;
    const int wn   = (wave & 1) * 64;
    const int quad = lane >> 4, r16 = lane & 15;

    floatx4 acc[4][4];
    #pragma unroll
    for (int i = 0; i < 4; ++i)
        #pragma unroll
        for (int j = 0; j < 4; ++j)
            acc[i][j] = (floatx4){0.f, 0.f, 0.f, 0.f};

    const int ar = tid >> 2, ac = (tid & 3) * 8;

    for (int k0 = 0; k0 < K; k0 += 32) {
        #pragma unroll
        for (int c = 0; c < 2; ++c) {
            const int row = c * 64 + ar;
            *(short8*)&As[row][ac] =
                *(const short8*)(Ap + (size_t)(bM * 128 + row) * (size_t)lda + (size_t)(k0 + ac));
            *(short8*)&Bs[row][ac] =
                *(const short8*)(Bp + (size_t)(bN * 128 + row) * (size_t)ldb + (size_t)(k0 + ac));
        }
        __syncthreads();

        short8 af[4], bfr[4];
        #pragma unroll
        for (int i = 0; i < 4; ++i) af[i]  = *(const short8*)&As[wm + i * 16 + r16][quad * 8];
        #pragma unroll
        for (int j = 0; j < 4; ++j) bfr[j] = *(const short8*)&Bs[wn + j * 16 + r16][quad * 8];
        #pragma unroll
        for (int i = 0; i < 4; ++i)
            #pragma unroll
            for (int j = 0; j < 4; ++j)
                acc[i][j] = __builtin_amdgcn_mfma_f32_16x16x32_bf16(af[i], bfr[j], acc[i][j], 0, 0, 0);
        __syncthreads();
    }

    const bool of32 = (OSRC == SRC_F32) || (OSRC == SRC_RT && rtf);
    #pragma unroll
    for (int j = 0; j < 4; ++j) {
        const int gc = bN * 128 + wn + j * 16 + r16;
        float bb = 0.0f;
        if (HAS_BIAS)
            bb = rtf ? ((const float*)bias)[gc]
                     : __bfloat162float(((const __hip_bfloat16*)bias)[gc]);
        #pragma unroll
        for (int i = 0; i < 4; ++i) {
            #pragma unroll
            for (int rg = 0; rg < 4; ++rg) {
                const int gr = bM * 128 + wm + i * 16 + quad * 4 + rg;
                float v = acc[i][j][rg] * alpha + bb;
                if (of32)
                    ((float*)Cp)[(size_t)gr * (size_t)ldc + gc] = v;
                else
                    ((__hip_bfloat16*)Cp)[(size_t)gr * (size_t)ldc + gc] = __float2bfloat16(v);
            }
        }
    }
}

// ---------------- single-sweep fused attention (16 rows/block, CAP=256) -------------
// Block = 16 Q-rows x 1 head, 256 threads (4 waves). All waves share the 16 rows;
// wave w handles col-tiles (w) and (w+4) of each 128-col K-tile. Running row-max is
// always <= M_final, so threshold rmax-1 <= M_final-1 keeps every sparsemax support
// element (z > tau >= M_final-1); Michelot on the candidate list yields the exact tau.
__global__ __launch_bounds__(256)
void attn_fused_k(const short* __restrict__ Qb, const short* __restrict__ Kb,
                  const short* __restrict__ Vb, short* __restrict__ Ob)
{
    __shared__ __align__(16) short sQ[16][72];
    __shared__ __align__(16) short sK[128][72];
    __shared__ float cval[16][CAP];
    __shared__ unsigned short cidx[16][CAP];
    __shared__ unsigned rmax[16];
    __shared__ int cnt[16];
    __shared__ float stau[16];

    const int tid  = threadIdx.x;
    const int lane = tid & 63, wave = tid >> 6;
    const int quad = lane >> 4, r16 = lane & 15;
    const int row0 = blockIdx.x * 16;
    const int h    = blockIdx.y;
    const int myrow = quad * 4;   // + rg

    if (tid < 16) { rmax[tid] = 0u; cnt[tid] = 0; }
    if (tid < 128) {
        const int r = tid >> 3, c = (tid & 7) * 8;
        *(short8*)&sQ[r][c] = *(const short8*)(Qb + (size_t)(row0 + r) * 1024 + h * 64 + c);
    }
    __syncthreads();

    const short8 a0 = *(const short8*)&sQ[r16][quad * 8];
    const short8 a1 = *(const short8*)&sQ[r16][32 + quad * 8];

    for (int s0 = 0; s0 < 2048; s0 += 128) {
        #pragma unroll
        for (int i = 0; i < 4; ++i) {
            const int kr = (tid >> 3) + 32 * i, c = (tid & 7) * 8;
            *(short8*)&sK[kr][c] = *(const short8*)(Kb + (size_t)(s0 + kr) * 1024 + h * 64 + c);
        }
        __syncthreads();

        floatx4 acc[2];
        #pragma unroll
        for (int t = 0; t < 2; ++t) {
            const int ct = (wave + 4 * t) * 16;
            const short8 b0 = *(const short8*)&sK[ct + r16][quad * 8];
            const short8 b1 = *(const short8*)&sK[ct + r16][32 + quad * 8];
            floatx4 a = (floatx4){0.f, 0.f, 0.f, 0.f};
            a = __builtin_amdgcn_mfma_f32_16x16x32_bf16(a0, b0, a, 0, 0, 0);
            a = __builtin_amdgcn_mfma_f32_16x16x32_bf16(a1, b1, a, 0, 0, 0);
            #pragma unroll
            for (int rg = 0; rg < 4; ++rg) a[rg] *= 0.125f;
            acc[t] = a;
        }

        // tile row-max: fold over t, 4-shuffle fold over r16, one atomicMax per row
        #pragma unroll
        for (int rg = 0; rg < 4; ++rg) {
            float m = fmaxf(acc[0][rg], acc[1][rg]);
            #pragma unroll
            for (int off = 1; off < 16; off <<= 1)
                m = fmaxf(m, __shfl_xor(m, off, 64));
            if (r16 == 0) atomicMax(&rmax[myrow + rg], fmap(m));
        }
        __syncthreads();   // rmax current; also gates next sK overwrite vs this tile's reads

        // append candidates (rare; atomic contention negligible)
        #pragma unroll
        for (int rg = 0; rg < 4; ++rg) {
            const int row = myrow + rg;
            const float thr = funmap(rmax[row]) - 1.0f;
            #pragma unroll
            for (int t = 0; t < 2; ++t) {
                const float val = acc[t][rg];
                if (val >= thr) {
                    const int p = atomicAdd(&cnt[row], 1);
                    if (p < CAP) {
                        cval[row][p] = val;
                        cidx[row][p] = (unsigned short)(s0 + (wave + 4 * t) * 16 + r16);
                    }
                }
            }
        }
    }
    __syncthreads();   // all appends done

    // ---- Michelot tau per row (4 rows per wave, 4 candidates/lane, shuffle-only) ----
    for (int rr = 0; rr < 4; ++rr) {
        const int r = wave * 4 + rr;
        const int n = min(cnt[r], CAP);
        float c0[4];
        #pragma unroll
        for (int i = 0; i < 4; ++i) {
            const int ix = lane + i * 64;
            c0[i] = (ix < n) ? cval[r][ix] : -3.0e38f;
        }
        float tau = -3.0e38f, prevc = -1.0f;
        for (int it = 0; it < 24; ++it) {
            float s = 0.f, c = 0.f;
            #pragma unroll
            for (int i = 0; i < 4; ++i)
                if (c0[i] > tau) { s += c0[i]; c += 1.f; }
            #pragma unroll
            for (int off = 1; off < 64; off <<= 1) {
                s += __shfl_xor(s, off, 64);
                c += __shfl_xor(c, off, 64);
            }
            if (c == prevc) break;
            prevc = c;
            tau = (s - 1.0f) / c;
        }
        if (lane == 0) stau[r] = tau;
    }
    __syncthreads();

    // ---- PV: ballot-compact support to list front (p stored), then unrolled gather --
    for (int rr = 0; rr < 4; ++rr) {
        const int r = wave * 4 + rr;
        const float tau = stau[r];
        const int n = min(cnt[r], CAP);

        float p[4];
        unsigned short ii[4];
        #pragma unroll
        for (int i = 0; i < 4; ++i) {
            const int ix = lane + i * 64;
            p[i]  = (ix < n) ? cval[r][ix] - tau : 0.f;
            ii[i] = (ix < n) ? cidx[r][ix] : 0;
        }
        const unsigned long long pre = (1ULL << lane) - 1ULL;
        int base = 0;
        #pragma unroll
        for (int i = 0; i < 4; ++i) {
            const unsigned long long m = __ballot(p[i] > 0.f);
            const int w = base + __popcll(m & pre);
            if (p[i] > 0.f) { cval[r][w] = p[i]; cidx[r][w] = ii[i]; }
            base += __popcll(m);
        }
        const int msup = base;

        // gather: lane = output col; 4-deep independent loads
        const unsigned short* vb = (const unsigned short*)Vb + (size_t)h * 64 + lane;
        float a0 = 0.f, a1 = 0.f, a2 = 0.f, a3 = 0.f;
        int j = 0;
        for (; j + 4 <= msup; j += 4) {
            const float q0 = cval[r][j],     q1 = cval[r][j + 1];
            const float q2 = cval[r][j + 2], q3 = cval[r][j + 3];
            const int   k0 = cidx[r][j],     k1 = cidx[r][j + 1];
            const int   k2 = cidx[r][j + 2], k3 = cidx[r][j + 3];
            a0 += q0 * bf2f(vb[(size_t)k0 * 1024]);
            a1 += q1 * bf2f(vb[(size_t)k1 * 1024]);
            a2 += q2 * bf2f(vb[(size_t)k2 * 1024]);
            a3 += q3 * bf2f(vb[(size_t)k3 * 1024]);
        }
        for (; j < msup; ++j)
            a0 += cval[r][j] * bf2f(vb[(size_t)cidx[r][j] * 1024]);

        Ob[((size_t)h * 2048 + row0 + r) * 64 + lane] = f2bf(a0 + a1 + a2 + a3);
    }
}

extern "C" void kernel_launch(void* const* d_in, const int* in_sizes, int n_in,
                              void* d_out, int out_size, void* d_ws, size_t ws_size,
                              hipStream_t stream)
{
    (void)in_sizes; (void)n_in; (void)out_size; (void)ws_size;

    const void* queries = d_in[0];
    const void* keys    = d_in[1];
    // d_in[2] ("values") unused by the reference.
    const void* Wq = d_in[3];
    const void* bq = d_in[4];
    const void* Wk = d_in[5];
    const void* bk = d_in[6];
    const void* Wv = d_in[7];
    const void* bv = d_in[8];
    const void* Wo = d_in[9];
    const void* bo = d_in[10];

    const int L = 2048, DM = 1024;
    const size_t LD = (size_t)L * DM;   // 2M elements

    int*   flag = (int*)d_ws;
    short* Qc  = (short*)((char*)d_ws + 256);  // bf16 queries      [2048,1024]
    short* Kc  = Qc + LD;                      // bf16 keys         [2048,1024]
    short* WqT = Kc + LD;                      // bf16 Wq^T         [1024,1024]
    short* WkT = WqT + (size_t)DM * DM;
    short* WvT = WkT + (size_t)DM * DM;
    short* WoT = WvT + (size_t)DM * DM;
    short* Qb  = WoT + (size_t)DM * DM;        // [2048,1024]
    short* Kb  = Qb + LD;
    short* Vb  = Kb + LD;
    short* Ob  = Vb + LD;                      // [H,2048,64] contiguous (== mixed view)

    dim3 blk(256);

    // 0) dtype detection
    detect_k<<<dim3(1), dim3(64), 0, stream>>>((const short*)queries, 4096, flag);

    // p1) convert queries/keys -> bf16
    convert2_k<<<dim3((unsigned)(LD / 2048), 1, 2), blk, 0, stream>>>(
        queries, keys, Qc, Kc, flag);

    // p2) transpose-convert the 4 weight matrices -> bf16 [N][K]
    {
        TP4 p;
        p.s[0] = Wq; p.s[1] = Wk; p.s[2] = Wv; p.s[3] = Wo;
        p.d[0] = WqT; p.d[1] = WkT; p.d[2] = WvT; p.d[3] = WoT;
        transpose4_k<<<dim3(DM / 64, DM / 64, 4), blk, 0, stream>>>(p, DM, DM, flag);
    }

    // 1) Kb = Kc @ WkT + bk
    gemm128_bt_k<SRC_BF16, true><<<dim3(DM / 128, L / 128), blk, 0, stream>>>(
        Kc, DM, WkT, DM, bk, Kb, DM, DM, 1.0f, flag);
    // 2) Qb = Qc @ WqT + bq
    gemm128_bt_k<SRC_BF16, true><<<dim3(DM / 128, L / 128), blk, 0, stream>>>(
        Qc, DM, WqT, DM, bq, Qb, DM, DM, 1.0f, flag);
    // 3) Vb = Kb @ WvT + bv   (reference quirk: V from key projection)
    gemm128_bt_k<SRC_BF16, true><<<dim3(DM / 128, L / 128), blk, 0, stream>>>(
        Kb, DM, WvT, DM, bv, Vb, DM, DM, 1.0f, flag);

    // 4) single-sweep fused attention (scores never reach HBM)
    attn_fused_k<<<dim3(L / 16, 16), blk, 0, stream>>>(Qb, Kb, Vb, Ob);

    // 5) out = Ob(viewed [2048,1024]) @ WoT + bo -> d_out (dtype per flag)
    gemm128_bt_k<SRC_RT, true><<<dim3(DM / 128, L / 128), blk, 0, stream>>>(
        Ob, DM, WoT, DM, bo, d_out, DM, DM, 1.0f, flag);
}

// Round 9
// 283.083 us; speedup vs baseline: 1.6181x; 1.2630x over previous
//
#include <hip/hip_runtime.h>
#include <hip/hip_bf16.h>

// Hopfield sparsemax attention, MI355X gfx950.
// B=1, L=S=2048, D_MODEL=1024, H=16, DK=64. Inputs fp32 (runtime-detected), output per flag.
//
// Round-9:
//   0.  detect dtype -> flag
//   p1. Qc/Kc = bf16(queries/keys)        [2048,1024]
//   p2. W*T = bf16(W^T)                   [1024,1024] x4 (LDS-tiled transpose)
//   1.  {Qb,Kb} projections batched via grid.z (64x64-tile GEMM, 1024 blocks = 4/CU)
//   2.  Vb = Kb @ WvT + bv                (ref quirk: V from key projection)
//   3.  attn_fused v3: 32 Q-rows x 256-col K-tiles (8 iters), packed bf16|idx candidates
//       (CAP=256), running-row-max threshold (superset of sparsemax support), per-wave
//       Michelot + ballot-compact + sparse PV gather. Scores never reach HBM.
//   4.  out = Ob @ WoT + bo

typedef __attribute__((ext_vector_type(8))) short short8;
typedef __attribute__((ext_vector_type(4))) float floatx4;

#define SRC_BF16 0
#define SRC_F32  1
#define SRC_RT   2
#define CAP 256

__device__ __forceinline__ short f2bf(float f) {
    __hip_bfloat16 h = __float2bfloat16(f);
    return *reinterpret_cast<const short*>(&h);
}
__device__ __forceinline__ unsigned short f2bfu(float f) {
    __hip_bfloat16 h = __float2bfloat16(f);
    return *reinterpret_cast<const unsigned short*>(&h);
}
__device__ __forceinline__ float bf2f(unsigned short u) {
    return __uint_as_float(((unsigned)u) << 16);
}
// monotone float->uint map (order-preserving for all finite floats)
__device__ __forceinline__ unsigned fmap(float f) {
    unsigned u = __float_as_uint(f);
    return (u & 0x80000000u) ? ~u : (u | 0x80000000u);
}
__device__ __forceinline__ float funmap(unsigned u) {
    return (u & 0x80000000u) ? __uint_as_float(u ^ 0x80000000u) : __uint_as_float(~u);
}

// Detect input dtype: decode first n shorts as bf16; fp32-read-as-bf16 almost surely
// yields |x|>1e10 / inf / NaN. One 64-thread block.
__global__ void detect_k(const short* __restrict__ q, int n, int* __restrict__ flag)
{
    const int tid = threadIdx.x;
    int bad = 0;
    for (int i = tid; i < n; i += 64) {
        float f = bf2f((unsigned short)q[i]);
        if (!(fabsf(f) < 1e10f)) bad = 1;
    }
    unsigned long long m = __ballot(bad != 0);
    if (tid == 0) *flag = (m != 0ULL) ? 1 : 0;
}

// Flat convert (fp32|bf16 per flag) -> bf16. z selects one of two sources.
__global__ __launch_bounds__(256)
void convert2_k(const void* __restrict__ s0, const void* __restrict__ s1,
                short* __restrict__ d0, short* __restrict__ d1,
                const int* __restrict__ dflag)
{
    const void* s = blockIdx.z ? s1 : s0;
    short* d = blockIdx.z ? d1 : d0;
    const size_t i = ((size_t)blockIdx.x * 256 + threadIdx.x) * 8;
    short8 o;
    if (*dflag) {
        const float4 f0 = ((const float4*)((const float*)s + i))[0];
        const float4 f1 = ((const float4*)((const float*)s + i))[1];
        o[0] = f2bf(f0.x); o[1] = f2bf(f0.y); o[2] = f2bf(f0.z); o[3] = f2bf(f0.w);
        o[4] = f2bf(f1.x); o[5] = f2bf(f1.y); o[6] = f2bf(f1.z); o[7] = f2bf(f1.w);
    } else {
        o = *(const short8*)((const short*)s + i);
    }
    *(short8*)(d + i) = o;
}

// Batched weight transpose: 4 matrices [R,C] -> bf16 [C,R], selected by blockIdx.z.
struct TP4 {
    const void* s[4];
    short* d[4];
};
__global__ __launch_bounds__(256)
void transpose4_k(TP4 p, int R, int C, const int* __restrict__ dflag)
{
    __shared__ short T[64][72];
    const int tid = threadIdx.x;
    const int bC = blockIdx.x, bR = blockIdx.y;
    const void* src = p.s[blockIdx.z];
    short* dst = p.d[blockIdx.z];
    const bool f32 = (*dflag != 0);

    const int colg = (tid & 7) * 8;
    #pragma unroll
    for (int h = 0; h < 2; ++h) {
        const int row = (tid >> 3) + 32 * h;
        const size_t idx = (size_t)(bR * 64 + row) * (size_t)C + (size_t)(bC * 64 + colg);
        short e[8];
        if (f32) {
            const float4 f0 = ((const float4*)((const float*)src + idx))[0];
            const float4 f1 = ((const float4*)((const float*)src + idx))[1];
            e[0] = f2bf(f0.x); e[1] = f2bf(f0.y); e[2] = f2bf(f0.z); e[3] = f2bf(f0.w);
            e[4] = f2bf(f1.x); e[5] = f2bf(f1.y); e[6] = f2bf(f1.z); e[7] = f2bf(f1.w);
        } else {
            short8 s = *(const short8*)((const short*)src + idx);
            #pragma unroll
            for (int j = 0; j < 8; ++j) e[j] = s[j];
        }
        #pragma unroll
        for (int j = 0; j < 8; ++j) T[colg + j][row] = e[j];
    }
    __syncthreads();
    #pragma unroll
    for (int h = 0; h < 2; ++h) {
        const int orow = (tid >> 3) + 32 * h;
        const int ocolg = (tid & 7) * 8;
        const size_t idx = (size_t)(bC * 64 + orow) * (size_t)R + (size_t)(bR * 64 + ocolg);
        *(short8*)(dst + idx) = *(const short8*)&T[orow][ocolg];
    }
}

// ---------------- 64x64-tile GEMM, bf16 A [2048,1024] x bf16 Bt [1024,1024] ----------
// C = A@Bt^T + bias. Two independent jobs selectable via blockIdx.z (batching Q & K
// projections doubles grid -> 4 blocks/CU). All dims fixed: M=2048, N=K=lda=ldb=ldc=1024.
struct GJ { const short* A; const short* B; const void* bias; void* C; };

template<int OSRC>
__global__ __launch_bounds__(256)
void gemm64_bt_k(GJ j0, GJ j1, const int* __restrict__ dflag)
{
    __shared__ __align__(16) short As[64][40];
    __shared__ __align__(16) short Bs[64][40];

    const GJ j = blockIdx.z ? j1 : j0;
    const int rtf = *dflag;

    const int tid  = threadIdx.x;
    const int bN   = blockIdx.x, bM = blockIdx.y;
    const int lane = tid & 63, wave = tid >> 6;
    const int wm   = (wave >> 1) * 32;
    const int wn   = (wave & 1) * 32;
    const int quad = lane >> 4, r16 = lane & 15;

    floatx4 acc[2][2];
    #pragma unroll
    for (int i = 0; i < 2; ++i)
        #pragma unroll
        for (int jj = 0; jj < 2; ++jj)
            acc[i][jj] = (floatx4){0.f, 0.f, 0.f, 0.f};

    const int ar = tid >> 2, ac = (tid & 3) * 8;

    for (int k0 = 0; k0 < 1024; k0 += 32) {
        *(short8*)&As[ar][ac] =
            *(const short8*)(j.A + (size_t)(bM * 64 + ar) * 1024 + (size_t)(k0 + ac));
        *(short8*)&Bs[ar][ac] =
            *(const short8*)(j.B + (size_t)(bN * 64 + ar) * 1024 + (size_t)(k0 + ac));
        __syncthreads();

        short8 a0 = *(const short8*)&As[wm + r16][quad * 8];
        short8 a1 = *(const short8*)&As[wm + 16 + r16][quad * 8];
        short8 b0 = *(const short8*)&Bs[wn + r16][quad * 8];
        short8 b1 = *(const short8*)&Bs[wn + 16 + r16][quad * 8];

        acc[0][0] = __builtin_amdgcn_mfma_f32_16x16x32_bf16(a0, b0, acc[0][0], 0, 0, 0);
        acc[0][1] = __builtin_amdgcn_mfma_f32_16x16x32_bf16(a0, b1, acc[0][1], 0, 0, 0);
        acc[1][0] = __builtin_amdgcn_mfma_f32_16x16x32_bf16(a1, b0, acc[1][0], 0, 0, 0);
        acc[1][1] = __builtin_amdgcn_mfma_f32_16x16x32_bf16(a1, b1, acc[1][1], 0, 0, 0);
        __syncthreads();
    }

    const bool of32 = (OSRC == SRC_F32) || (OSRC == SRC_RT && rtf);
    #pragma unroll
    for (int jj = 0; jj < 2; ++jj) {
        const int gc = bN * 64 + wn + jj * 16 + r16;
        const float bb = rtf ? ((const float*)j.bias)[gc]
                             : bf2f(((const unsigned short*)j.bias)[gc]);
        #pragma unroll
        for (int i = 0; i < 2; ++i) {
            #pragma unroll
            for (int rg = 0; rg < 4; ++rg) {
                const int gr = bM * 64 + wm + i * 16 + quad * 4 + rg;
                const float v = acc[i][jj][rg] + bb;
                if (of32)
                    ((float*)j.C)[(size_t)gr * 1024 + gc] = v;
                else
                    ((__hip_bfloat16*)j.C)[(size_t)gr * 1024 + gc] = __float2bfloat16(v);
            }
        }
    }
}

// ---------------- fused attention v3: 32 rows x 256-col K-tiles, packed candidates ----
// Block = 32 Q-rows x 1 head, 256 threads. Wave w: rows sp..sp+15 (sp=(w>>1)*16),
// col half hf=w&1 -> 8 col-tiles of each 256-col K-tile. Per tile: MFMA scores,
// fold row-max (7 fmax + 4 shuffles), atomicMax to shared running max, barrier,
// append candidates z >= rmax-1 packed as (bf16(z)<<16)|kidx. rmax <= M_final always,
// so the keep-set is a superset of the sparsemax support (z > tau >= M_final-1).
// Michelot + PV run per-wave on owned rows (no barriers): exact tau on bf16-rounded
// candidates (sum p = 1 preserved), ballot-compact, 4-deep sparse V gather.
__global__ __launch_bounds__(256)
void attn_fused_k(const short* __restrict__ Qb, const short* __restrict__ Kb,
                  const short* __restrict__ Vb, short* __restrict__ Ob)
{
    __shared__ __align__(16) short sQ[32][72];
    __shared__ __align__(16) short sK[256][72];
    __shared__ unsigned cpk[32][CAP];
    __shared__ unsigned rmax[32];
    __shared__ int cnt[32];

    const int tid  = threadIdx.x;
    const int lane = tid & 63, wave = tid >> 6;
    const int quad = lane >> 4, r16 = lane & 15;
    const int row0 = blockIdx.x * 32;
    const int h    = blockIdx.y;
    const int sp   = (wave >> 1) * 16;
    const int hf   = wave & 1;
    const int myrow = sp + quad * 4;   // + rg

    if (tid < 32) { rmax[tid] = 0u; cnt[tid] = 0; }
    {
        const int r = tid >> 3, c = (tid & 7) * 8;
        *(short8*)&sQ[r][c] = *(const short8*)(Qb + (size_t)(row0 + r) * 1024 + h * 64 + c);
    }
    __syncthreads();

    const short8 a0 = *(const short8*)&sQ[sp + r16][quad * 8];
    const short8 a1 = *(const short8*)&sQ[sp + r16][32 + quad * 8];

    for (int s0 = 0; s0 < 2048; s0 += 256) {
        // stage 256x64 K-tile: 8 rows/thread
        #pragma unroll
        for (int i = 0; i < 8; ++i) {
            const int kr = (tid >> 3) + 32 * i, c = (tid & 7) * 8;
            *(short8*)&sK[kr][c] = *(const short8*)(Kb + (size_t)(s0 + kr) * 1024 + h * 64 + c);
        }
        __syncthreads();

        floatx4 acc[8];
        #pragma unroll
        for (int t = 0; t < 8; ++t) {
            const int ct = (hf + 2 * t) * 16;
            const short8 b0 = *(const short8*)&sK[ct + r16][quad * 8];
            const short8 b1 = *(const short8*)&sK[ct + r16][32 + quad * 8];
            floatx4 a = (floatx4){0.f, 0.f, 0.f, 0.f};
            a = __builtin_amdgcn_mfma_f32_16x16x32_bf16(a0, b0, a, 0, 0, 0);
            a = __builtin_amdgcn_mfma_f32_16x16x32_bf16(a1, b1, a, 0, 0, 0);
            #pragma unroll
            for (int rg = 0; rg < 4; ++rg) a[rg] *= 0.125f;
            acc[t] = a;
        }

        // fold tile row-max, post to shared running max
        #pragma unroll
        for (int rg = 0; rg < 4; ++rg) {
            float m = acc[0][rg];
            #pragma unroll
            for (int t = 1; t < 8; ++t) m = fmaxf(m, acc[t][rg]);
            #pragma unroll
            for (int off = 1; off < 16; off <<= 1)
                m = fmaxf(m, __shfl_xor(m, off, 64));
            if (r16 == 0) atomicMax(&rmax[myrow + rg], fmap(m));
        }
        __syncthreads();   // rmax complete for this tile; sK reads done

        // append candidates z >= rmax-1 (packed); overlaps next tile's staging safely
        #pragma unroll
        for (int rg = 0; rg < 4; ++rg) {
            const int row = myrow + rg;
            const float thr = funmap(rmax[row]) - 1.0f;
            #pragma unroll
            for (int t = 0; t < 8; ++t) {
                const float val = acc[t][rg];
                if (val >= thr) {
                    const int p = atomicAdd(&cnt[row], 1);
                    if (p < CAP) {
                        cpk[row][p] = ((unsigned)f2bfu(val) << 16)
                                    | (unsigned)(s0 + (hf + 2 * t) * 16 + r16);
                    }
                }
            }
        }
    }
    __syncthreads();   // all appends visible

    // ---- per-wave Michelot + PV on owned rows (wave w: rows w*8 .. w*8+7) ----
    const unsigned long long pre = (1ULL << lane) - 1ULL;
    for (int rr = 0; rr < 8; ++rr) {
        const int r = wave * 8 + rr;
        const int n = min(cnt[r], CAP);

        float v[4];
        unsigned short ii[4];
        #pragma unroll
        for (int i = 0; i < 4; ++i) {
            const int ix = lane + i * 64;
            if (ix < n) {
                const unsigned u = cpk[r][ix];
                v[i] = bf2f((unsigned short)(u >> 16));
                ii[i] = (unsigned short)(u & 0xFFFFu);
            } else { v[i] = -3.0e38f; ii[i] = 0; }
        }

        float tau = -3.0e38f, prevc = -1.0f;
        for (int it = 0; it < 24; ++it) {
            float s = 0.f, c = 0.f;
            #pragma unroll
            for (int i = 0; i < 4; ++i)
                if (v[i] > tau) { s += v[i]; c += 1.f; }
            #pragma unroll
            for (int off = 1; off < 64; off <<= 1) {
                s += __shfl_xor(s, off, 64);
                c += __shfl_xor(c, off, 64);
            }
            if (c == prevc) break;
            prevc = c;
            tau = (s - 1.0f) / c;
        }

        // ballot-compact support (p>0) to list front, p packed bf16
        int base = 0;
        #pragma unroll
        for (int i = 0; i < 4; ++i) {
            const float p = v[i] - tau;
            const unsigned long long m = __ballot(p > 0.f);
            const int w = base + __popcll(m & pre);
            if (p > 0.f) cpk[r][w] = ((unsigned)f2bfu(p) << 16) | (unsigned)ii[i];
            base += __popcll(m);
        }
        const int msup = base;

        // sparse PV gather: lane = output col; 4-deep independent loads
        const unsigned short* vb = (const unsigned short*)Vb + (size_t)h * 64 + lane;
        float a0 = 0.f, a1 = 0.f, a2 = 0.f, a3 = 0.f;
        int jj = 0;
        for (; jj + 4 <= msup; jj += 4) {
            const unsigned u0 = cpk[r][jj],     u1 = cpk[r][jj + 1];
            const unsigned u2 = cpk[r][jj + 2], u3 = cpk[r][jj + 3];
            a0 += bf2f((unsigned short)(u0 >> 16)) * bf2f(vb[(size_t)(u0 & 0xFFFFu) * 1024]);
            a1 += bf2f((unsigned short)(u1 >> 16)) * bf2f(vb[(size_t)(u1 & 0xFFFFu) * 1024]);
            a2 += bf2f((unsigned short)(u2 >> 16)) * bf2f(vb[(size_t)(u2 & 0xFFFFu) * 1024]);
            a3 += bf2f((unsigned short)(u3 >> 16)) * bf2f(vb[(size_t)(u3 & 0xFFFFu) * 1024]);
        }
        for (; jj < msup; ++jj) {
            const unsigned u0 = cpk[r][jj];
            a0 += bf2f((unsigned short)(u0 >> 16)) * bf2f(vb[(size_t)(u0 & 0xFFFFu) * 1024]);
        }
        Ob[((size_t)h * 2048 + row0 + r) * 64 + lane] = f2bf(a0 + a1 + a2 + a3);
    }
}

extern "C" void kernel_launch(void* const* d_in, const int* in_sizes, int n_in,
                              void* d_out, int out_size, void* d_ws, size_t ws_size,
                              hipStream_t stream)
{
    (void)in_sizes; (void)n_in; (void)out_size; (void)ws_size;

    const void* queries = d_in[0];
    const void* keys    = d_in[1];
    // d_in[2] ("values") unused by the reference.
    const void* Wq = d_in[3];
    const void* bq = d_in[4];
    const void* Wk = d_in[5];
    const void* bk = d_in[6];
    const void* Wv = d_in[7];
    const void* bv = d_in[8];
    const void* Wo = d_in[9];
    const void* bo = d_in[10];

    const int L = 2048, DM = 1024;
    const size_t LD = (size_t)L * DM;   // 2M elements

    int*   flag = (int*)d_ws;
    short* Qc  = (short*)((char*)d_ws + 256);  // bf16 queries      [2048,1024]
    short* Kc  = Qc + LD;                      // bf16 keys         [2048,1024]
    short* WqT = Kc + LD;                      // bf16 Wq^T         [1024,1024]
    short* WkT = WqT + (size_t)DM * DM;
    short* WvT = WkT + (size_t)DM * DM;
    short* WoT = WvT + (size_t)DM * DM;
    short* Qb  = WoT + (size_t)DM * DM;        // [2048,1024]
    short* Kb  = Qb + LD;
    short* Vb  = Kb + LD;
    short* Ob  = Vb + LD;                      // [H,2048,64] contiguous (== mixed view)

    dim3 blk(256);

    // 0) dtype detection
    detect_k<<<dim3(1), dim3(64), 0, stream>>>((const short*)queries, 4096, flag);

    // p1) convert queries/keys -> bf16
    convert2_k<<<dim3((unsigned)(LD / 2048), 1, 2), blk, 0, stream>>>(
        queries, keys, Qc, Kc, flag);

    // p2) transpose-convert the 4 weight matrices -> bf16 [N][K]
    {
        TP4 p;
        p.s[0] = Wq; p.s[1] = Wk; p.s[2] = Wv; p.s[3] = Wo;
        p.d[0] = WqT; p.d[1] = WkT; p.d[2] = WvT; p.d[3] = WoT;
        transpose4_k<<<dim3(DM / 64, DM / 64, 4), blk, 0, stream>>>(p, DM, DM, flag);
    }

    // 1) Qb & Kb projections batched (1024 blocks = 4/CU)
    {
        GJ jq{(const short*)Qc, WqT, bq, Qb};
        GJ jk{(const short*)Kc, WkT, bk, Kb};
        gemm64_bt_k<SRC_BF16><<<dim3(DM / 64, L / 64, 2), blk, 0, stream>>>(jq, jk, flag);
    }
    // 2) Vb = Kb @ WvT + bv   (reference quirk: V from key projection)
    {
        GJ jv{(const short*)Kb, WvT, bv, Vb};
        gemm64_bt_k<SRC_BF16><<<dim3(DM / 64, L / 64, 1), blk, 0, stream>>>(jv, jv, flag);
    }

    // 3) fused attention (scores never reach HBM)
    attn_fused_k<<<dim3(L / 32, 16), blk, 0, stream>>>(Qb, Kb, Vb, Ob);

    // 4) out = Ob(viewed [2048,1024]) @ WoT + bo -> d_out (dtype per flag)
    {
        GJ jo{(const short*)Ob, WoT, bo, d_out};
        gemm64_bt_k<SRC_RT><<<dim3(DM / 64, L / 64, 1), blk, 0, stream>>>(jo, jo, flag);
    }
}